// Round 1
// 449.538 us; speedup vs baseline: 1.0032x; 1.0032x over previous
//
#include <hip/hip_runtime.h>

// AdaConv2d as pre-pass + implicit GEMM (bf16 MFMA 16x16x32, fp32 acc).
//
// Pre-pass 1: xp[b][h'][w'][ic] bf16, h',w' in [0,58), zero-padded border
//             (border zeroing folded in; no giant memset).
// Pre-pass 2: wq[d][r][oc][ic] bf16 = kernel_base[oc][ic][r] * kernel_mask[d][ic][r].
// Main: per (pixel-tile 64, b): C[pix][oc] = sum_{r, ic} xp[pix+off_r][ic] * wq[d][r][oc][ic]
//       64x256 block tile, 4 waves (each 64 pix x 64 oc, 4x4 acc), K-chunk 32,
//       DOUBLE-BUFFERED LDS, 2-phase pipeline: stage chunk c+1 via global_load_lds
//       while computing chunk c; ONE barrier per chunk (implicit vmcnt drain at the
//       barrier lands after compute instead of before it).

typedef __bf16 v8bf __attribute__((ext_vector_type(8)));
typedef float  v4f  __attribute__((ext_vector_type(4)));
typedef unsigned short v8us __attribute__((ext_vector_type(8)));

#define IC_  128
#define OC_  256
#define HH   56
#define WW_  56
#define HW_  3136
#define PW   58                      // padded spatial dim
#define XP_PER_B (PW * PW * IC_)     // 430592 elems
#define WQ_ELEMS (4 * 9 * OC_ * IC_) // 1179648 elems

__device__ __forceinline__ unsigned short f2bf(float f) {
    unsigned u = __builtin_bit_cast(unsigned, f);
    u += 0x7fffu + ((u >> 16) & 1u);    // RNE
    return (unsigned short)(u >> 16);
}

typedef __attribute__((address_space(3))) unsigned int lds_u32_t;
typedef const __attribute__((address_space(1))) unsigned int gbl_u32_t;

__device__ __forceinline__ void gload_lds16(const unsigned short* gsrc, unsigned short* ldst) {
    // dest = (wave-uniform ldst) + lane*16B; per-lane gsrc; 16B per lane.
    __builtin_amdgcn_global_load_lds((gbl_u32_t*)gsrc,
                                     (lds_u32_t*)(unsigned int)(unsigned long long)(uintptr_t)ldst,
                                     16, 0, 0);
}

// ---- pre-pass 1: x[b][ic][h][w] fp32 -> xp[b][h+1][w+1][ic] bf16, plus border zeroing ----
__global__ __launch_bounds__(256)
void transpose_pad(const float* __restrict__ x, unsigned short* __restrict__ xp)
{
    __shared__ unsigned short lt[IC_ * 58];   // [ic][w], stride 58 (4-way instead of 8-way read conflict)
    const int blk = blockIdx.x;               // b*56 + h
    const int b = blk / HH, h = blk % HH;
    const int t = threadIdx.x;
    const float* xb = x + (size_t)b * IC_ * HW_ + h * WW_;
    // phase 1: 7168 floats = 1792 float4 loads; 256 threads x 7
    #pragma unroll
    for (int i = 0; i < 7; ++i) {
        int e4 = t + i * 256;                 // < 1792
        int ic = e4 / 14;
        int w4 = (e4 - ic * 14) * 4;
        v4f v = *(const v4f*)&xb[ic * HW_ + w4];
        unsigned lo = (unsigned)f2bf(v[0]) | ((unsigned)f2bf(v[1]) << 16);
        unsigned hi = (unsigned)f2bf(v[2]) | ((unsigned)f2bf(v[3]) << 16);
        unsigned* dst = (unsigned*)&lt[ic * 58 + w4];   // dword-aligned (w4 mult of 4, 58 even)
        dst[0] = lo;
        dst[1] = hi;
    }
    __syncthreads();
    unsigned short* xpb = xp + (size_t)b * XP_PER_B + (size_t)(h + 1) * PW * IC_;
    #pragma unroll
    for (int i = 0; i < 4; ++i) {
        int s = t + i * 256;
        if (s < 896) {                        // 56 w * 16 ic-groups
            int w = s >> 4, icg = s & 15;
            unsigned short v[8];
            #pragma unroll
            for (int j = 0; j < 8; ++j) v[j] = lt[(icg * 8 + j) * 58 + w];
            *(v8us*)&xpb[(w + 1) * IC_ + icg * 8] = *(const v8us*)v;
        }
    }
    // border cols w'=0 and w'=57 of this row: 2 * 128 elems = 32 x v8us
    if (t < 32) {
        int col = (t >> 4) * 57;              // 0 or 57
        *(v8us*)&xpb[(size_t)col * IC_ + (t & 15) * 8] = (v8us)(unsigned short)0;
    }
    // border rows h'=0 (from h==0 block) and h'=57 (from h==55 block): PW*IC = 7424 elems = 928 x v8us
    if (h == 0 || h == HH - 1) {
        unsigned short* row = xp + (size_t)b * XP_PER_B + (h == 0 ? 0 : (size_t)(PW - 1) * PW * IC_);
        for (int s = t; s < 928; s += 256)
            *(v8us*)&row[(size_t)s * 8] = (v8us)(unsigned short)0;
    }
}

// ---- pre-pass 2: wq[d][r][oc][ic] = bf16(kbase[oc][ic][r] * kmask[d][ic][r]) ----
__global__ __launch_bounds__(256)
void build_weights(const float* __restrict__ kbase, const float* __restrict__ kmask,
                   unsigned short* __restrict__ wq)
{
    int t  = blockIdx.x * 256 + threadIdx.x;   // < 1179648
    int ic = t & 127;
    int oc = (t >> 7) & 255;
    int rd = t >> 15;                          // d*9 + r
    int r  = rd % 9, d = rd / 9;
    float v = kbase[oc * 1152 + ic * 9 + r] * kmask[d * 1152 + ic * 9 + r];
    wq[t] = f2bf(v);
}

// ---- main: implicit GEMM, 2-phase double-buffered pipeline ----
__global__ __launch_bounds__(256, 4)
void adaconv_main(const unsigned short* __restrict__ xp,
                  const unsigned short* __restrict__ wq,
                  const int* __restrict__ demog,
                  float* __restrict__ out)
{
    __shared__ unsigned short lds_a[2][64 * 32];    // 2 x 4 KB
    __shared__ unsigned short lds_b[2][256 * 32];   // 2 x 16 KB  -> 40 KB total

    const int t    = threadIdx.x;
    const int lane = t & 63;
    const int quad = lane >> 4;
    const int l15  = lane & 15;
    const int wid  = __builtin_amdgcn_readfirstlane(t >> 6);   // 0..3, oc quarter

    const int mtile = blockIdx.x;     // 0..48
    const int b     = blockIdx.y;     // 0..63
    const int p0    = mtile * 64;
    const int d     = demog[b];

    // staging roles: thread t -> (pix = t>>2, icg = t&3) for A; (oc = t>>2 (+64j), icg) for B
    const int spix = p0 + (t >> 2);
    const int sh   = spix / WW_;
    const int sw   = spix - sh * WW_;
    const unsigned short* asrc = xp + (size_t)b * XP_PER_B
                               + (size_t)((sh + 1) * PW + (sw + 1)) * IC_ + (t & 3) * 8;
    const unsigned short* bsrc = wq + (size_t)d * 9 * OC_ * IC_
                               + (t >> 2) * IC_ + (t & 3) * 8;

    v4f acc[4][4];
    #pragma unroll
    for (int mi = 0; mi < 4; ++mi)
        #pragma unroll
        for (int ni = 0; ni < 4; ++ni)
            acc[mi][ni] = (v4f)0.0f;

    // chunk c (0..35): r = c>>2 (tap), icb = c&3 (ic 32-chunk)
    #define STAGE(buf, c)                                                              \
        do {                                                                           \
            const int r_   = (c) >> 2;                                                 \
            const int icb_ = (c) & 3;                                                  \
            const int toff_ = ((r_ / 3 - 1) * PW + (r_ % 3 - 1)) * IC_;                \
            const int ic0_  = icb_ * 32;                                               \
            gload_lds16(asrc + toff_ + ic0_, &lds_a[(buf)][wid * 512]);                \
            _Pragma("unroll")                                                          \
            for (int j = 0; j < 4; ++j)                                                \
                gload_lds16(bsrc + r_ * (OC_ * IC_) + j * 64 * IC_ + ic0_,             \
                            &lds_b[(buf)][wid * 512 + j * 2048]);                      \
        } while (0)

    STAGE(0, 0);
    __syncthreads();    // implicit vmcnt(0) drain: chunk 0 staged

    #pragma unroll
    for (int c = 0; c < 36; ++c) {
        const int cur = c & 1;
        if (c + 1 < 36) STAGE(cur ^ 1, c + 1);   // prefetch next chunk (overlaps compute below)

        v8us au[4], bu[4];
        #pragma unroll
        for (int mi = 0; mi < 4; ++mi)
            au[mi] = *(const v8us*)&lds_a[cur][(mi * 16 + l15) * 32 + quad * 8];
        #pragma unroll
        for (int ni = 0; ni < 4; ++ni)
            bu[ni] = *(const v8us*)&lds_b[cur][(wid * 64 + ni * 16 + l15) * 32 + quad * 8];

        #pragma unroll
        for (int mi = 0; mi < 4; ++mi) {
            v8bf a = __builtin_bit_cast(v8bf, au[mi]);
            #pragma unroll
            for (int ni = 0; ni < 4; ++ni) {
                v8bf bb = __builtin_bit_cast(v8bf, bu[ni]);
                acc[mi][ni] = __builtin_amdgcn_mfma_f32_16x16x32_bf16(a, bb, acc[mi][ni], 0, 0, 0);
            }
        }
        __syncthreads();   // one barrier per chunk; its vmcnt(0) drain covers the prefetch
    }
    #undef STAGE

    // epilogue: D row = quad*4+reg (pix), col = l15 (oc)
    float* ob = out + ((size_t)b * OC_ + wid * 64) * HW_ + p0;
    #pragma unroll
    for (int ni = 0; ni < 4; ++ni) {
        #pragma unroll
        for (int mi = 0; mi < 4; ++mi) {
            float* o = ob + (size_t)(ni * 16 + l15) * HW_ + mi * 16 + quad * 4;
            *(v4f*)o = acc[mi][ni];
        }
    }
}

extern "C" void kernel_launch(void* const* d_in, const int* in_sizes, int n_in,
                              void* d_out, int out_size, void* d_ws, size_t ws_size,
                              hipStream_t stream) {
    const float* x     = (const float*)d_in[0];
    const int*   demog = (const int*)d_in[1];
    const float* kbase = (const float*)d_in[2];
    const float* kmask = (const float*)d_in[3];
    float* out = (float*)d_out;

    unsigned short* xp = (unsigned short*)d_ws;
    unsigned short* wq = xp + (size_t)64 * XP_PER_B;
    transpose_pad<<<64 * HH, 256, 0, stream>>>(x, xp);
    build_weights<<<WQ_ELEMS / 256, 256, 0, stream>>>(kbase, kmask, wq);
    adaconv_main<<<dim3(49, 64), 256, 0, stream>>>(xp, wq, demog, out);
}